// Round 20
// baseline (126.917 us; speedup 1.0000x reference)
//
#include <hip/hip_runtime.h>
#include <math.h>

#define B_    8
#define Q_    900
#define NCLS_ 11
#define NANC_ 100
#define H_    200
#define W_    200
#define C_    256
#define CHNK_ 113           // rank chunk per block in topk
#define WIN_  25            // pixels per wave-task
#define NWIN_ (W_ / WIN_)   // 8 windows per row
#define NTASK_ (B_ * H_ * NWIN_)   // 12800 wave-tasks

typedef float f32x4_ __attribute__((ext_vector_type(4)));

// ---------------------------------------------------------------------------
// Kernel 1: scores + rank + box transform (R12, proven).
// ---------------------------------------------------------------------------
__global__ __launch_bounds__(128) void segdet_topk_kernel(
    const float* __restrict__ pred_boxes,
    const float* __restrict__ pred_logits,
    const float* __restrict__ view,
    int*  __restrict__ ws_idx,
    int4* __restrict__ ws_box)
{
    const int b     = blockIdx.x >> 3;
    const int chunk = blockIdx.x & 7;
    const int tid   = threadIdx.x;

    __shared__ __align__(16) float sc[Q_];

    for (int q2 = tid; q2 < Q_; q2 += 128) {
        const float* l = pred_logits + (b * Q_ + q2) * NCLS_;
        float v[NCLS_];
        float m = -INFINITY;
        #pragma unroll
        for (int i = 0; i < NCLS_; ++i) { v[i] = l[i]; m = fmaxf(m, v[i]); }
        float s = 0.0f, e10 = -INFINITY;
        #pragma unroll
        for (int i = 0; i < NCLS_; ++i) {
            float e = expf(v[i] - m);
            s += e;
            if (i < NCLS_ - 1) e10 = fmaxf(e10, e);
        }
        sc[q2] = e10 / s;
    }
    __syncthreads();

    const int q = chunk * CHNK_ + tid;
    if (tid < CHNK_ && q < Q_) {
        const float my = sc[q];
        int rank = 0;
        #pragma unroll 4
        for (int j4 = 0; j4 < Q_ / 4; ++j4) {
            const float4 o = *(const float4*)&sc[j4 * 4];
            const int j = j4 * 4;
            rank += (o.x > my) || (o.x == my && (j + 0) < q);
            rank += (o.y > my) || (o.y == my && (j + 1) < q);
            rank += (o.z > my) || (o.z == my && (j + 2) < q);
            rank += (o.w > my) || (o.w == my && (j + 3) < q);
        }
        if (rank < NANC_) {
            const float* bx = pred_boxes + (b * Q_ + q) * 4;
            double cx = (double)bx[0], cy = (double)bx[1];
            double w  = exp((double)bx[2]);
            double h  = exp((double)bx[3]);
            double p[5] = { cx - 0.5 * w, cy - 0.5 * h,
                            cx + 0.5 * w, cy + 0.5 * h, 1.0 };
            const float* v5 = view + b * 25;
            int ico[4];
            #pragma unroll
            for (int i = 0; i < 4; ++i) {
                double acc = 0.0;
                #pragma unroll
                for (int j = 0; j < 5; ++j) acc += (double)v5[i * 5 + j] * p[j];
                ico[i] = (int)acc;                    // trunc == astype(int32)
            }
            int x0 = min(max(ico[0], 0), W_);
            int y0 = min(max(ico[1], 0), H_);
            int x1 = min(max(ico[2], 0), W_);
            int y1 = min(max(ico[3], 0), H_);
            const int slot = b * NANC_ + rank;
            ws_idx[slot] = q;
            ws_box[slot] = make_int4(x0, y0, x1, y1);
        }
    }
}

__device__ __forceinline__ void nt_store4(float* p, f32x4_ v) {
    __builtin_nontemporal_store(v, (f32x4_*)p);
}

// ---------------------------------------------------------------------------
// Kernel 2: BEV splat — wave-independent window tasks, ZERO barriers.
// Mechanism under test: every prior ~100us variant marched all waves of a
// block through a barrier-locked preamble and a synchronized finish, so each
// CU's store issue had CORRELATED gaps; the 6.9 TB/s fill kernel has zero
// barriers and never stops storing. Here one wave = one 25-pixel window of
// one row: lane-parallel 2-iter box scan (ballots) builds the window's
// init-coverage list + event mini-list in per-wave LDS (rank-sorted, k-order
// preserved), init acc = k-order sum of covering boxes (4-batched loads),
// then a 25-pixel walk with on-demand event applies. Waves never sync ->
// preamble gaps decorrelate across 12,800 independent streams.
// Numerics: same k-order coverage sums (intra-pixel open/close interleave
// differs -> fp delta ~1e-6 << 0.405 threshold); exact zeros via cnt==0.
// ---------------------------------------------------------------------------
__global__ __launch_bounds__(256) void segdet_bev_kernel(
    const float* __restrict__ box_feats,    // [B,Q,C]
    const int*   __restrict__ ws_idx,       // [B,NANC]
    const int4*  __restrict__ ws_box,       // [B,NANC]
    float* __restrict__ bev,                // [B,H,W,C]
    float* __restrict__ mask)               // [B,H,W]
{
    const int ln   = threadIdx.x & 63;
    const int wv   = threadIdx.x >> 6;
    const int task = blockIdx.x * 4 + wv;   // 0..NTASK_-1
    if (task >= NTASK_) return;

    const int rid = task / NWIN_;           // row id 0..1599
    const int jw  = task % NWIN_;           // window 0..7
    const int b   = rid / H_;
    const int h   = rid % H_;
    const int w0  = jw * WIN_;
    const int wlast = w0 + WIN_ - 1;

    __shared__ int s_ini[4][104];           // init-coverage q list (k-order)
    __shared__ int s_ev [4][204];           // raw events: q | pix<<10 | sign<<31
    __shared__ int s_evs[4][204];           // pixel-sorted events

    const unsigned long long lmask = (1ull << ln) - 1ull;

    // ---- lane-parallel box scan: init list + window event list (k-order)
    int nini = 0, nev = 0;
    #pragma unroll
    for (int it = 0; it < 2; ++it) {
        const int k = it * 64 + ln;
        bool ic = false, oc = false, cc = false;
        int qi = 0, x0 = 0, x1 = 0;
        if (k < NANC_) {
            const int4 bx = ws_box[b * NANC_ + k];
            qi = ws_idx[b * NANC_ + k];
            x0 = bx.x; x1 = bx.z;
            const bool act = (bx.y <= h) && (h < bx.w) && (x0 < x1);
            ic = act && (x0 <= w0) && (w0 < x1);             // covers w0
            oc = act && (x0 >  w0) && (x0 <= wlast);         // opens in window
            cc = act && (x1 >  w0) && (x1 <= wlast);         // closes in window
        }
        unsigned long long bi = __ballot(ic);
        int pos = nini + (int)__popcll(bi & lmask);
        if (ic) s_ini[wv][pos] = qi;
        nini += (int)__popcll(bi);

        unsigned long long bo = __ballot(oc);
        pos = nev + (int)__popcll(bo & lmask);
        if (oc) s_ev[wv][pos] = qi | (x0 << 10);
        nev += (int)__popcll(bo);

        unsigned long long bc = __ballot(cc);
        pos = nev + (int)__popcll(bc & lmask);
        if (cc) s_ev[wv][pos] = (int)((unsigned)qi | ((unsigned)x1 << 10)
                                      | 0x80000000u);
        nev += (int)__popcll(bc);
    }

    // ---- rank-sort events by (pix, list idx) — lane-parallel, stable
    for (int base = 0; base < nev; base += 64) {
        const int e = base + ln;
        if (e < nev) {
            const int me = s_ev[wv][e];
            const int mypix = (me >> 10) & 0xFF;
            int rank = 0;
            for (int j = 0; j < nev; ++j) {
                const int pj = (s_ev[wv][j] >> 10) & 0xFF;
                rank += (pj < mypix) || (pj == mypix && j < e);
            }
            s_evs[wv][rank] = me;
        }
    }

    // ---- init acc at pixel w0: k-order sum over covering boxes (4-batched)
    const float* fbase = box_feats + (size_t)b * Q_ * C_ + ln * 4;
    f32x4_ acc = {0.f, 0.f, 0.f, 0.f};
    int cnt = nini;
    int i = 0;
    for (; i + 4 <= nini; i += 4) {
        const int q0 = s_ini[wv][i + 0];
        const int q1 = s_ini[wv][i + 1];
        const int q2 = s_ini[wv][i + 2];
        const int q3 = s_ini[wv][i + 3];
        const f32x4_ a0 = *(const f32x4_*)(fbase + (size_t)q0 * C_);
        const f32x4_ a1 = *(const f32x4_*)(fbase + (size_t)q1 * C_);
        const f32x4_ a2 = *(const f32x4_*)(fbase + (size_t)q2 * C_);
        const f32x4_ a3 = *(const f32x4_*)(fbase + (size_t)q3 * C_);
        acc += a0; acc += a1; acc += a2; acc += a3;      // sequential k-order
    }
    for (; i < nini; ++i) {
        const int q0 = s_ini[wv][i];
        acc += *(const f32x4_*)(fbase + (size_t)q0 * C_);
    }

    // ---- 25-pixel walk: sorted events applied at their pixels, NT stores
    float* obase = bev + ((size_t)rid * W_ + w0) * C_ + ln * 4;
    float* mrow  = mask + (size_t)rid * W_ + w0;

    int p = 0;
    for (int d = 0; d < WIN_; ++d) {
        const int w = w0 + d;
        while (p < nev && ((s_evs[wv][p] >> 10) & 0xFF) == w) {
            const int ent = s_evs[wv][p];
            const f32x4_ f = *(const f32x4_*)(fbase + (size_t)(ent & 0x3FF) * C_);
            if (ent < 0) { acc -= f; --cnt; }
            else         { acc += f; ++cnt; }
            ++p;
        }
        if (cnt == 0) acc = (f32x4_){0.f, 0.f, 0.f, 0.f};   // exact zeros
        nt_store4(obase + (size_t)d * C_, acc);
        if (ln == 0) __builtin_nontemporal_store((cnt > 0) ? 1.0f : 0.0f,
                                                 &mrow[d]);
    }
}

// ---------------------------------------------------------------------------
extern "C" void kernel_launch(void* const* d_in, const int* in_sizes, int n_in,
                              void* d_out, int out_size, void* d_ws, size_t ws_size,
                              hipStream_t stream) {
    const float* pred_boxes  = (const float*)d_in[0];
    const float* pred_logits = (const float*)d_in[1];
    const float* box_feats   = (const float*)d_in[2];
    const float* view        = (const float*)d_in[3];

    float* bev  = (float*)d_out;
    float* mask = bev + (size_t)B_ * H_ * W_ * C_;

    int*  ws_idx = (int*)d_ws;                            // 800 ints
    int4* ws_box = (int4*)((char*)d_ws + 3200);           // 800 int4 (16B aligned)

    segdet_topk_kernel<<<B_ * 8, 128, 0, stream>>>(pred_boxes, pred_logits, view,
                                                   ws_idx, ws_box);
    segdet_bev_kernel<<<NTASK_ / 4, 256, 0, stream>>>(box_feats, ws_idx, ws_box,
                                                      bev, mask);
}

// Round 21
// 98.986 us; speedup vs baseline: 1.2822x; 1.2822x over previous
//
#include <hip/hip_runtime.h>
#include <math.h>

#define B_    8
#define Q_    900
#define NCLS_ 11
#define NANC_ 100
#define H_    200
#define W_    200
#define C_    256
#define HHALF 100
#define CHNK_ 113           // rank chunk per block in topk
#define CHEV_ 16            // events per staged chunk (path B)
#define FCAP_ 58            // all-LDS path capacity (58 KB feats)
#define SPAN_ (W_ / 4)      // 50 contiguous pixels per wave

typedef float f32x4_ __attribute__((ext_vector_type(4)));

// ---------------------------------------------------------------------------
// Kernel 1: scores + rank + box transform (R12, proven).
// ---------------------------------------------------------------------------
__global__ __launch_bounds__(128) void segdet_topk_kernel(
    const float* __restrict__ pred_boxes,
    const float* __restrict__ pred_logits,
    const float* __restrict__ view,
    int*  __restrict__ ws_idx,
    int4* __restrict__ ws_box)
{
    const int b     = blockIdx.x >> 3;
    const int chunk = blockIdx.x & 7;
    const int tid   = threadIdx.x;

    __shared__ __align__(16) float sc[Q_];

    for (int q2 = tid; q2 < Q_; q2 += 128) {
        const float* l = pred_logits + (b * Q_ + q2) * NCLS_;
        float v[NCLS_];
        float m = -INFINITY;
        #pragma unroll
        for (int i = 0; i < NCLS_; ++i) { v[i] = l[i]; m = fmaxf(m, v[i]); }
        float s = 0.0f, e10 = -INFINITY;
        #pragma unroll
        for (int i = 0; i < NCLS_; ++i) {
            float e = expf(v[i] - m);
            s += e;
            if (i < NCLS_ - 1) e10 = fmaxf(e10, e);
        }
        sc[q2] = e10 / s;
    }
    __syncthreads();

    const int q = chunk * CHNK_ + tid;
    if (tid < CHNK_ && q < Q_) {
        const float my = sc[q];
        int rank = 0;
        #pragma unroll 4
        for (int j4 = 0; j4 < Q_ / 4; ++j4) {
            const float4 o = *(const float4*)&sc[j4 * 4];
            const int j = j4 * 4;
            rank += (o.x > my) || (o.x == my && (j + 0) < q);
            rank += (o.y > my) || (o.y == my && (j + 1) < q);
            rank += (o.z > my) || (o.z == my && (j + 2) < q);
            rank += (o.w > my) || (o.w == my && (j + 3) < q);
        }
        if (rank < NANC_) {
            const float* bx = pred_boxes + (b * Q_ + q) * 4;
            double cx = (double)bx[0], cy = (double)bx[1];
            double w  = exp((double)bx[2]);
            double h  = exp((double)bx[3]);
            double p[5] = { cx - 0.5 * w, cy - 0.5 * h,
                            cx + 0.5 * w, cy + 0.5 * h, 1.0 };
            const float* v5 = view + b * 25;
            int ico[4];
            #pragma unroll
            for (int i = 0; i < 4; ++i) {
                double acc = 0.0;
                #pragma unroll
                for (int j = 0; j < 5; ++j) acc += (double)v5[i * 5 + j] * p[j];
                ico[i] = (int)acc;                    // trunc == astype(int32)
            }
            int x0 = min(max(ico[0], 0), W_);
            int y0 = min(max(ico[1], 0), H_);
            int x1 = min(max(ico[2], 0), W_);
            int y1 = min(max(ico[3], 0), H_);
            const int slot = b * NANC_ + rank;
            ws_idx[slot] = q;
            ws_box[slot] = make_int4(x0, y0, x1, y1);
        }
    }
}

__device__ __forceinline__ void nt_store4(float* p, f32x4_ v) {
    __builtin_nontemporal_store(v, (f32x4_*)p);
}

__device__ __forceinline__ void gload_lds_16(const float* g, float* l) {
    __builtin_amdgcn_global_load_lds(
        (const __attribute__((address_space(1))) void*)g,
        (__attribute__((address_space(3))) void*)l,
        16, 0, 0);
}

// ---------------------------------------------------------------------------
// Kernel 2: BEV splat — best-known configuration (R18, 98.6us):
// contiguous 50-px per-wave store spans, two-path walk (all-LDS for
// nact<=FCAP_, chunk-staged otherwise), depth-2 pipelined feature reads,
// center-out LPT ordering, NT stores, empty-row fast path.
// ---------------------------------------------------------------------------
__global__ __launch_bounds__(256) void segdet_bev_kernel(
    const float* __restrict__ box_feats,
    const int*   __restrict__ ws_idx,
    const int4*  __restrict__ ws_box,
    float* __restrict__ bev,
    float* __restrict__ mask)
{
    // center-out (LPT) row order
    const int hidx = blockIdx.x / B_;
    const int b    = blockIdx.x % B_;
    const int h    = (hidx & 1) ? (HHALF - 1 - (hidx >> 1)) : (HHALF + (hidx >> 1));

    const int tid = threadIdx.x;
    const int ln  = tid & 63;
    const int wv  = tid >> 6;

    __shared__ __align__(16) char s_mem[FCAP_ * C_ * 4];  // A: feats, B: chunk dbuf
    __shared__ int s_box[NANC_];            // x0 | x1<<8 | q<<16
    __shared__ int s_nact;
    __shared__ int s_nopen[W_];
    __shared__ int s_ofs[W_ + 1];
    __shared__ int s_ent[2 * NANC_];
    __shared__ int s_wsum[4];

    float (*s_feat)[C_] = (float (*)[C_])s_mem;           // path A view
    float* s_chunkf     = (float*)s_mem;                  // path B view (2x16KB)

    // ---- wave-0 ballot compaction (deterministic k-order)
    if (tid < 64) {
        int na = 0;
        #pragma unroll
        for (int it = 0; it < 2; ++it) {
            int k = it * 64 + ln;
            bool act = false;
            int packed = 0;
            if (k < NANC_) {
                int4 bx = ws_box[b * NANC_ + k];
                int qi  = ws_idx[b * NANC_ + k];
                act = (bx.y <= h) && (h < bx.w) && (bx.x < bx.z);
                packed = bx.x | (bx.z << 8) | (qi << 16);
            }
            unsigned long long ball = __ballot(act);
            int pos = na + (int)__popcll(ball & ((1ull << ln) - 1ull));
            if (act) s_box[pos] = packed;
            na += (int)__popcll(ball);
        }
        if (ln == 0) s_nact = na;
    }
    __syncthreads();                                   // B1

    const int nact = s_nact;
    float* obase = bev + (size_t)(b * H_ + h) * W_ * C_ + ln * 4;
    float* mrow  = mask + (size_t)(b * H_ + h) * W_;

    const int span_lo = wv * SPAN_;
    const int span_hi = span_lo + SPAN_;

    // ---- empty-row fast path (contiguous spans)
    if (nact == 0) {
        const f32x4_ z = {0.f, 0.f, 0.f, 0.f};
        for (int w = span_lo; w < span_hi; ++w)
            nt_store4(obase + (size_t)w * C_, z);
        if (tid < W_) __builtin_nontemporal_store(0.0f, &mrow[tid]);
        return;
    }

    // ---- per-pixel open/close counts + coverage (mask)
    int ntot = 0;
    if (tid < W_) {
        int nopen = 0, nclose = 0, cov = 0;
        for (int k = 0; k < nact; ++k) {
            int pk = s_box[k];
            int x0 = pk & 0xFF, x1 = (pk >> 8) & 0xFF;
            nopen  += (x0 == tid);
            nclose += (x1 == tid);
            cov    += (x0 <= tid) && (tid < x1);
        }
        s_nopen[tid] = nopen;
        ntot = nopen + nclose;
        __builtin_nontemporal_store((cov > 0) ? 1.0f : 0.0f, &mrow[tid]);
    }

    // ---- shuffle scan + cross-wave combine
    int incl = ntot;
    #pragma unroll
    for (int d = 1; d < 64; d <<= 1) {
        int u = __shfl_up(incl, d);
        incl = (ln >= d) ? incl + u : incl;
    }
    if (ln == 63) s_wsum[wv] = incl;
    __syncthreads();                                   // B2

    int prev = 0;
    #pragma unroll
    for (int j = 0; j < 4; ++j) prev += (j < wv) ? s_wsum[j] : 0;
    const int ne = s_wsum[0] + s_wsum[1] + s_wsum[2] + s_wsum[3];
    if (tid < W_) s_ofs[tid] = prev + incl - ntot;
    if (tid == 0) s_ofs[W_] = ne;
    __syncthreads();                                   // B3

    // ---- CSR entry scatter: ent = q | rank<<10 | pix<<17 | sign<<31 (k-order)
    if (tid < nact) {
        int pk = s_box[tid];
        int x0 = pk & 0xFF, x1 = (pk >> 8) & 0xFF, q = pk >> 16;
        int ro = 0, rc = 0;
        for (int j = 0; j < tid; ++j) {
            int pj = s_box[j];
            ro += ((pj & 0xFF) == x0);
            rc += (((pj >> 8) & 0xFF) == x1);
        }
        s_ent[s_ofs[x0] + ro] = q | (tid << 10) | (x0 << 17);
        if (x1 < W_)
            s_ent[s_ofs[x1] + s_nopen[x1] + rc] =
                (int)((unsigned)q | ((unsigned)tid << 10) |
                      ((unsigned)x1 << 17) | 0x80000000u);
    }
    __syncthreads();                                   // B4 (s_ent ready)

    const float* fbase = box_feats + (size_t)b * Q_ * C_ + ln * 4;

    if (nact <= FCAP_) {
        // ========== PATH A: all-LDS, depth-2 pipelined, contiguous span =====
        for (int k = wv; k < nact; k += 4) {
            const int q = s_box[k] >> 16;              // uniform LDS read
            gload_lds_16(fbase + (size_t)q * C_, &s_feat[k][0]);
        }
        __syncthreads();                               // staging complete

        f32x4_ acc = {0.f, 0.f, 0.f, 0.f};
        int cnt = 0;
        int w = span_lo;
        int e0 = s_ent[0];                             // ne >= 1 here
        int e1 = s_ent[(1 < ne) ? 1 : 0];
        f32x4_ f0 = *(const f32x4_*)&s_feat[(e0 >> 10) & 0x7F][ln * 4];
        f32x4_ f1 = *(const f32x4_*)&s_feat[(e1 >> 10) & 0x7F][ln * 4];
        for (int e = 0; e < ne; ++e) {
            const int i2 = (e + 2 < ne) ? (e + 2) : (ne - 1);
            const int e2 = s_ent[i2];
            const f32x4_ f2 = *(const f32x4_*)&s_feat[(e2 >> 10) & 0x7F][ln * 4];
            const int pe_raw = (e0 >> 17) & 0xFF;
            const int pe = (pe_raw < span_hi) ? pe_raw : span_hi;
            for (; w < pe; ++w)                        // sequential NT stream
                nt_store4(obase + (size_t)w * C_, acc);
            if (pe_raw >= span_hi) break;              // span finished; acc done
            if (e0 < 0) { acc -= f0; --cnt; }
            else        { acc += f0; ++cnt; }
            if (cnt == 0) acc = (f32x4_){0.f, 0.f, 0.f, 0.f};
            e0 = e1; e1 = e2; f0 = f1; f1 = f2;        // named-reg rotation
        }
        for (; w < span_hi; ++w)
            nt_store4(obase + (size_t)w * C_, acc);
    } else {
        // ========== PATH B: chunk-staged, depth-2, contiguous span ==========
        const int nchunk = (ne + CHEV_ - 1) / CHEV_;

#define STAGE_(CI)                                                            \
    {                                                                         \
        const int base_ = (CI) * CHEV_;                                       \
        float* dst_ = s_chunkf + ((CI) & 1) * (CHEV_ * C_);                   \
        _Pragma("unroll")                                                     \
        for (int j = 0; j < 4; ++j) {                                         \
            const int e_ = base_ + wv * 4 + j;                                \
            if (e_ < ne) {                                                    \
                const int q_ = s_ent[e_] & 0x3FF;                             \
                gload_lds_16(fbase + (size_t)q_ * C_,                         \
                             dst_ + (wv * 4 + j) * C_);                       \
            }                                                                 \
        }                                                                     \
    }

        STAGE_(0);
        __syncthreads();

        f32x4_ acc = {0.f, 0.f, 0.f, 0.f};
        int cnt = 0;
        int w = span_lo;
        for (int ci = 0; ci < nchunk; ++ci) {
            if (ci + 1 < nchunk) STAGE_(ci + 1);
            const int ebeg = ci * CHEV_;
            const int eend = (ne < ebeg + CHEV_) ? ne : (ebeg + CHEV_);
            const float* cb = s_chunkf + (ci & 1) * (CHEV_ * C_);
            int e0 = s_ent[ebeg];
            int e1 = s_ent[(ebeg + 1 < eend) ? (ebeg + 1) : (eend - 1)];
            f32x4_ f0 = *(const f32x4_*)&cb[0 * C_ + ln * 4];
            f32x4_ f1 = *(const f32x4_*)
                &cb[(size_t)(((ebeg + 1 < eend) ? (ebeg + 1) : (eend - 1)) - ebeg)
                    * C_ + ln * 4];
            for (int e = ebeg; e < eend; ++e) {
                const int i2 = (e + 2 < eend) ? (e + 2) : (eend - 1);
                const int e2 = s_ent[i2];
                const f32x4_ f2 = *(const f32x4_*)&cb[(size_t)(i2 - ebeg) * C_
                                                      + ln * 4];
                const int pe_raw = (e0 >> 17) & 0xFF;
                const int pe = (pe_raw < span_hi) ? pe_raw : span_hi;
                for (; w < pe; ++w)                    // sequential NT stream
                    nt_store4(obase + (size_t)w * C_, acc);
                if (e0 < 0) { acc -= f0; --cnt; }      // no break (barriers)
                else        { acc += f0; ++cnt; }
                if (cnt == 0) acc = (f32x4_){0.f, 0.f, 0.f, 0.f};
                e0 = e1; e1 = e2; f0 = f1; f1 = f2;
            }
            __syncthreads();
        }
#undef STAGE_
        for (; w < span_hi; ++w)
            nt_store4(obase + (size_t)w * C_, acc);
    }
}

// ---------------------------------------------------------------------------
extern "C" void kernel_launch(void* const* d_in, const int* in_sizes, int n_in,
                              void* d_out, int out_size, void* d_ws, size_t ws_size,
                              hipStream_t stream) {
    const float* pred_boxes  = (const float*)d_in[0];
    const float* pred_logits = (const float*)d_in[1];
    const float* box_feats   = (const float*)d_in[2];
    const float* view        = (const float*)d_in[3];

    float* bev  = (float*)d_out;
    float* mask = bev + (size_t)B_ * H_ * W_ * C_;

    int*  ws_idx = (int*)d_ws;                            // 800 ints
    int4* ws_box = (int4*)((char*)d_ws + 3200);           // 800 int4 (16B aligned)

    segdet_topk_kernel<<<B_ * 8, 128, 0, stream>>>(pred_boxes, pred_logits, view,
                                                   ws_idx, ws_box);
    segdet_bev_kernel<<<B_ * H_, 256, 0, stream>>>(box_feats, ws_idx, ws_box,
                                                   bev, mask);
}